// Round 10
// baseline (2171.916 us; speedup 1.0000x reference)
//
#include <hip/hip_runtime.h>
#include <math.h>

#define S_LEN 512
#define BATCH 64
#define HSZ   512
#define G4    2048

typedef __attribute__((ext_vector_type(8))) short short8;
typedef __attribute__((ext_vector_type(4))) float f32x4;
typedef __attribute__((ext_vector_type(4))) unsigned u32x4;

// ---------------- Static device state ---------------------------------------
__device__ unsigned short g_xbf[(size_t)S_LEN * BATCH * HSZ]; // input as bf16 (32 MB)
__device__ unsigned short g_wbf[G4 * HSZ];                    // W_hh bf16
__device__ unsigned short g_wihbf[G4 * HSZ];                  // W_ih bf16
// h exchange in MFMA A-fragment order: [(kk*64 + quad*16 + m)*8 + e],
// hi/lo bf16 planes (hi+lo ~= fp23), double-buffered, per batch-group.
// R6-proven protocol: data stores -> vmcnt drain -> flag store; consumer
// polls flags then bulk-loads. (R8/R9 tagged-exchange attempts both failed
// with stub-identical zero output — reverted per pre-commitment.)
__device__ unsigned short g_hfhi[2][4][8192];
__device__ unsigned short g_hflo[2][4][8192];
__device__ unsigned g_flags2[4][16];          // monotonic, never reset

__device__ __forceinline__ unsigned short f2bf(float f) {  // RNE fp32->bf16
  unsigned u = __builtin_bit_cast(unsigned, f);
  u += 0x7fffu + ((u >> 16) & 1u);
  return (unsigned short)(u >> 16);
}
__device__ __forceinline__ float bf2f(unsigned short s) {
  return __builtin_bit_cast(float, (unsigned)s << 16);
}
__device__ __forceinline__ float sigmoidf_(float x) { return 1.0f / (1.0f + __expf(-x)); }

// ---------------- Kernel A: input fp32 -> bf16 -------------------------------
__global__ __launch_bounds__(256) void xcvt(const float* __restrict__ x) {
  const size_t i = ((size_t)blockIdx.x * 256 + threadIdx.x) * 8;
  const float4 a = *(const float4*)(x + i);
  const float4 b = *(const float4*)(x + i + 4);
  ushort4 o0, o1;
  o0.x = f2bf(a.x); o0.y = f2bf(a.y); o0.z = f2bf(a.z); o0.w = f2bf(a.w);
  o1.x = f2bf(b.x); o1.y = f2bf(b.y); o1.z = f2bf(b.z); o1.w = f2bf(b.w);
  *(ushort4*)(g_xbf + i) = o0;
  *(ushort4*)(g_xbf + i + 4) = o1;
}

// ---------------- Kernel B: W_hh / W_ih fp32 -> bf16 ------------------------
__global__ __launch_bounds__(256) void wcvt(const float* __restrict__ whh,
                                            const float* __restrict__ wih) {
  const int b = blockIdx.x;
  const float* src = (b < 1024) ? whh : wih;
  unsigned short* dst = (b < 1024) ? g_wbf : g_wihbf;
  const int i = ((b & 1023) * 256 + threadIdx.x) * 4;
  const float4 v = *(const float4*)(src + i);
  ushort4 o;
  o.x = f2bf(v.x); o.y = f2bf(v.y); o.z = f2bf(v.z); o.w = f2bf(v.w);
  *(ushort4*)(dst + i) = o;
}

// ---------------- Kernel C: x_proj = input @ W_ih^T + bias (bf16 MFMA) ------
// 128x128 tile, BK=32, identity-fragment LDS (conflict-free). NEW in R10:
// coalesced C-store via LDS transpose (was 64 scalar dword stores per lane).
__global__ __launch_bounds__(256) void xproj_mfma(
    const float* __restrict__ bih,
    const float* __restrict__ bhh,
    float* __restrict__ C)
{
  __shared__ unsigned short Af[4096];
  __shared__ unsigned short Bfs[4096];
  __shared__ float tbuf[32 * 132];      // transpose chunk: 32 m x 128 n, pad 132
  const int tid = threadIdx.x;
  const int l = tid & 63, w = tid >> 6;
  const int bm = blockIdx.x >> 4, bn = blockIdx.x & 15;
  const int m0 = bm << 7, n0 = bn << 7;

  const int c0 = tid, c1 = tid + 256;
  const int ms0 = c0 >> 6, q0 = (c0 >> 4) & 3, r0 = c0 & 15;
  const int ms1 = c1 >> 6, q1 = (c1 >> 4) & 3, r1 = c1 & 15;
  const size_t aoff0 = (size_t)(m0 + (ms0 << 4) + r0) * 512 + (q0 << 3);
  const size_t aoff1 = (size_t)(m0 + (ms1 << 4) + r1) * 512 + (q1 << 3);
  const size_t boff0 = (size_t)(n0 + (ms0 << 4) + r0) * 512 + (q0 << 3);
  const size_t boff1 = (size_t)(n0 + (ms1 << 4) + r1) * 512 + (q1 << 3);

  f32x4 acc[8][2];
  #pragma unroll
  for (int i = 0; i < 8; ++i) {
    acc[i][0] = (f32x4){0.f, 0.f, 0.f, 0.f};
    acc[i][1] = (f32x4){0.f, 0.f, 0.f, 0.f};
  }

  for (int kb = 0; kb < 512; kb += 32) {
    const uint4 a0 = *(const uint4*)(g_xbf + aoff0 + kb);
    const uint4 a1 = *(const uint4*)(g_xbf + aoff1 + kb);
    const uint4 b0 = *(const uint4*)(g_wihbf + boff0 + kb);
    const uint4 b1 = *(const uint4*)(g_wihbf + boff1 + kb);
    __syncthreads();
    *(uint4*)(Af + c0 * 8) = a0;
    *(uint4*)(Af + c1 * 8) = a1;
    *(uint4*)(Bfs + c0 * 8) = b0;
    *(uint4*)(Bfs + c1 * 8) = b1;
    __syncthreads();
    short8 bfr[2];
    bfr[0] = *(const short8*)(Bfs + ((w * 2 + 0) * 64 + l) * 8);
    bfr[1] = *(const short8*)(Bfs + ((w * 2 + 1) * 64 + l) * 8);
    #pragma unroll
    for (int ms = 0; ms < 8; ++ms) {
      const short8 af = *(const short8*)(Af + (ms * 64 + l) * 8);
      acc[ms][0] = __builtin_amdgcn_mfma_f32_16x16x32_bf16(af, bfr[0], acc[ms][0], 0, 0, 0);
      acc[ms][1] = __builtin_amdgcn_mfma_f32_16x16x32_bf16(af, bfr[1], acc[ms][1], 0, 0, 0);
    }
  }

  const int col = l & 15, quad = l >> 4;
  float bias[2];
  #pragma unroll
  for (int p = 0; p < 2; ++p) {
    const int n = n0 + ((w * 2 + p) << 4) + col;
    bias[p] = bih[n] + bhh[n];
  }
  // Coalesced store: 4 chunks of (32 m x 128 n) via LDS transpose.
  const int tm = tid >> 3;            // 0..31 m within chunk
  const int tn = (tid & 7) << 4;      // 0,16,..,112 n start (16 floats/thread)
  for (int c = 0; c < 4; ++c) {
    __syncthreads();                   // tbuf free (prev chunk consumed)
    #pragma unroll
    for (int ms = 0; ms < 2; ++ms)
      #pragma unroll
      for (int p = 0; p < 2; ++p)
        #pragma unroll
        for (int i = 0; i < 4; ++i)
          tbuf[((ms << 4) + (quad << 2) + i) * 132 + (w << 5) + (p << 4) + col]
              = acc[c * 2 + ms][p][i] + bias[p];
    __syncthreads();
    const int gm = m0 + (c << 5) + tm;
    float* dst = C + (size_t)gm * 2048 + n0 + tn;
    const float* src = tbuf + tm * 132 + tn;
    *(float4*)(dst)      = *(const float4*)(src);
    *(float4*)(dst + 4)  = *(const float4*)(src + 4);
    *(float4*)(dst + 8)  = *(const float4*)(src + 8);
    *(float4*)(dst + 12) = *(const float4*)(src + 12);
  }
}

// ---------------- Kernel D: persistent MFMA recurrence (R6 protocol) --------
// 64 blocks = 4 batch-groups (16 b) x 16 j-tiles (32 j). Wave g = gate g,
// 2 MFMA N-subtiles. W_hh bf16 B-frags in VGPRs. h exchanged in fragment
// order (identity staging, conflict-free LDS). Wave-0-only flag polling.
// R10 tweak: `out` result write moved AFTER publish+drain+flag (was inside
// the drained store window, adding its ack to the critical path).
__global__ __launch_bounds__(256, 1) void lstm_rec(
    const float* __restrict__ xproj,  // (S, B, 2048)
    const float* __restrict__ h0,     // (B, 512) fp32
    const float* __restrict__ c0,     // (B, 512) fp32
    float* __restrict__ out)          // (S,B,512) then h_T then c_T
{
  __shared__ unsigned short his[8192];  // A hi plane, fragment order
  __shared__ unsigned short los[8192];  // A lo plane
  __shared__ float gbuf[4 * 16 * 33];   // [gate][b][j] stride 33

  const int tid  = threadIdx.x;
  const int bg   = blockIdx.x & 3;      // batch group (16 batches)
  const int jt   = blockIdx.x >> 2;     // 0..15 j-tile
  const int b0   = bg << 4;
  const int j0   = jt << 5;             // 0..480
  const int lane = tid & 63;
  const int g    = tid >> 6;            // wave id == gate id
  const int m    = lane & 15;
  const int quad = lane >> 4;

  const unsigned base = __hip_atomic_load(&g_flags2[bg][jt], __ATOMIC_RELAXED,
                                          __HIP_MEMORY_SCOPE_AGENT);

  // Preload B-frags: wave g, subtile nt, K-step kk; B[n=lane&15][k=quad*8+j]
  short8 Bf[2][16];
  #pragma unroll
  for (int nt = 0; nt < 2; ++nt)
    #pragma unroll
    for (int kk = 0; kk < 16; ++kk) {
      const int row = (g << 9) + j0 + (nt << 4) + m;   // W_hh row <= 2047
      Bf[nt][kk] = *(const short8*)(g_wbf + row * 512 + kk * 32 + quad * 8);
    }

  // Epilogue ownership: thread -> (batch eb, j-pair ej, ej+1); c in registers
  const int eb = tid >> 4;
  const int ej = (tid & 15) << 1;
  float creg0 = c0[(size_t)(b0 + eb) * 512 + j0 + ej];
  float creg1 = c0[(size_t)(b0 + eb) * 512 + j0 + ej + 1];

  // Producer publish position (fragment order): kk=jt, quad=ej>>3, m=eb
  const int pub = (jt * 64 + ((ej >> 3) << 4) + eb) * 8 + (ej & 7);

  for (int t = 0; t < S_LEN; ++t) {
    // xproj prefetch (independent of h): 4 gates x float2
    const float* xpp = xproj + ((size_t)t * BATCH + b0 + eb) * G4 + j0 + ej;
    const float2 xpi = *(const float2*)(xpp);
    const float2 xpf = *(const float2*)(xpp + 512);
    const float2 xpg = *(const float2*)(xpp + 1024);
    const float2 xpo = *(const float2*)(xpp + 1536);

    if (t > 0) {
      if (g == 0) {
        const unsigned target = base + (unsigned)t;
        const int fl = lane & 15;
        for (;;) {
          const unsigned f = __hip_atomic_load(&g_flags2[bg][fl], __ATOMIC_RELAXED,
                                               __HIP_MEMORY_SCOPE_AGENT);
          if (__all((int)(f - target) >= 0)) break;
          __builtin_amdgcn_s_sleep(1);
        }
      }
      __syncthreads();  // release all waves to stage
      // Identity staging: global frag plane -> LDS frag plane (coherent loads)
      const unsigned short* hp = &g_hfhi[(t - 1) & 1][bg][tid * 8];
      const unsigned short* lp = &g_hflo[(t - 1) & 1][bg][tid * 8];
      u32x4 h0v, h1v, h2v, h3v, l0v, l1v, l2v, l3v;
      asm volatile(
          "global_load_dwordx4 %0, %8, off sc0 sc1\n\t"
          "global_load_dwordx4 %1, %9, off sc0 sc1\n\t"
          "global_load_dwordx4 %2, %10, off sc0 sc1\n\t"
          "global_load_dwordx4 %3, %11, off sc0 sc1\n\t"
          "global_load_dwordx4 %4, %12, off sc0 sc1\n\t"
          "global_load_dwordx4 %5, %13, off sc0 sc1\n\t"
          "global_load_dwordx4 %6, %14, off sc0 sc1\n\t"
          "global_load_dwordx4 %7, %15, off sc0 sc1\n\t"
          "s_waitcnt vmcnt(0)"
          : "=&v"(h0v), "=&v"(h1v), "=&v"(h2v), "=&v"(h3v),
            "=&v"(l0v), "=&v"(l1v), "=&v"(l2v), "=&v"(l3v)
          : "v"(hp), "v"(hp + 2048), "v"(hp + 4096), "v"(hp + 6144),
            "v"(lp), "v"(lp + 2048), "v"(lp + 4096), "v"(lp + 6144)
          : "memory");
      *(u32x4*)(his + tid * 8)        = h0v;
      *(u32x4*)(his + tid * 8 + 2048) = h1v;
      *(u32x4*)(his + tid * 8 + 4096) = h2v;
      *(u32x4*)(his + tid * 8 + 6144) = h3v;
      *(u32x4*)(los + tid * 8)        = l0v;
      *(u32x4*)(los + tid * 8 + 2048) = l1v;
      *(u32x4*)(los + tid * 8 + 4096) = l2v;
      *(u32x4*)(los + tid * 8 + 6144) = l3v;
    } else {
      // t==0: split h0 fp32 -> hi/lo fragment planes in LDS
      const int sr = tid >> 4;          // batch row 0..15
      const int sc = tid & 15;          // kk chunk 0..15
      const float* hp0 = h0 + (size_t)(b0 + sr) * 512 + sc * 32;
      #pragma unroll
      for (int q = 0; q < 4; ++q) {
        const float4 v0 = *(const float4*)(hp0 + q * 8);
        const float4 v1 = *(const float4*)(hp0 + q * 8 + 4);
        ushort4 h4a, l4a, h4b, l4b;
        h4a.x = f2bf(v0.x); l4a.x = f2bf(v0.x - bf2f(h4a.x));
        h4a.y = f2bf(v0.y); l4a.y = f2bf(v0.y - bf2f(h4a.y));
        h4a.z = f2bf(v0.z); l4a.z = f2bf(v0.z - bf2f(h4a.z));
        h4a.w = f2bf(v0.w); l4a.w = f2bf(v0.w - bf2f(h4a.w));
        h4b.x = f2bf(v1.x); l4b.x = f2bf(v1.x - bf2f(h4b.x));
        h4b.y = f2bf(v1.y); l4b.y = f2bf(v1.y - bf2f(h4b.y));
        h4b.z = f2bf(v1.z); l4b.z = f2bf(v1.z - bf2f(h4b.z));
        h4b.w = f2bf(v1.w); l4b.w = f2bf(v1.w - bf2f(h4b.w));
        const int dst = (sc * 64 + q * 16 + sr) * 8;
        *(ushort4*)(his + dst)     = h4a;
        *(ushort4*)(his + dst + 4) = h4b;
        *(ushort4*)(los + dst)     = l4a;
        *(ushort4*)(los + dst + 4) = l4b;
      }
    }
    __syncthreads();

    // MFMA: acc[nt] over K=512 (16 steps), A = hi + lo; wave-contiguous reads
    f32x4 acc0 = {0.f, 0.f, 0.f, 0.f};
    f32x4 acc1 = {0.f, 0.f, 0.f, 0.f};
    const unsigned short* ab = his + lane * 8;
    const unsigned short* lb = los + lane * 8;
    #pragma unroll
    for (int kk = 0; kk < 16; ++kk) {
      const short8 ah = *(const short8*)(ab + kk * 512);
      const short8 al = *(const short8*)(lb + kk * 512);
      acc0 = __builtin_amdgcn_mfma_f32_16x16x32_bf16(ah, Bf[0][kk], acc0, 0, 0, 0);
      acc1 = __builtin_amdgcn_mfma_f32_16x16x32_bf16(ah, Bf[1][kk], acc1, 0, 0, 0);
      acc0 = __builtin_amdgcn_mfma_f32_16x16x32_bf16(al, Bf[0][kk], acc0, 0, 0, 0);
      acc1 = __builtin_amdgcn_mfma_f32_16x16x32_bf16(al, Bf[1][kk], acc1, 0, 0, 0);
    }
    // C layout: col = lane&15 (j), row = quad*4+i (batch)
    #pragma unroll
    for (int i = 0; i < 4; ++i) {
      gbuf[g * 528 + (quad * 4 + i) * 33 + m]      = acc0[i];
      gbuf[g * 528 + (quad * 4 + i) * 33 + 16 + m] = acc1[i];
    }
    __syncthreads();

    // Epilogue: 2 cells per thread
    const float gi0 = gbuf[0 * 528 + eb * 33 + ej]     + xpi.x;
    const float gi1 = gbuf[0 * 528 + eb * 33 + ej + 1] + xpi.y;
    const float gf0 = gbuf[1 * 528 + eb * 33 + ej]     + xpf.x;
    const float gf1 = gbuf[1 * 528 + eb * 33 + ej + 1] + xpf.y;
    const float gg0 = gbuf[2 * 528 + eb * 33 + ej]     + xpg.x;
    const float gg1 = gbuf[2 * 528 + eb * 33 + ej + 1] + xpg.y;
    const float go0 = gbuf[3 * 528 + eb * 33 + ej]     + xpo.x;
    const float go1 = gbuf[3 * 528 + eb * 33 + ej + 1] + xpo.y;

    creg0 = sigmoidf_(gf0) * creg0 + sigmoidf_(gi0) * tanhf(gg0);
    creg1 = sigmoidf_(gf1) * creg1 + sigmoidf_(gi1) * tanhf(gg1);
    const float h0n = sigmoidf_(go0) * tanhf(creg0);
    const float h1n = sigmoidf_(go1) * tanhf(creg1);

    if (t < S_LEN - 1) {
      // Publish hi/lo fragment words for step t FIRST (critical path), drain,
      // flag; only then the out-result write (off critical path).
      const unsigned short hh0 = f2bf(h0n), hh1 = f2bf(h1n);
      const unsigned short ll0 = f2bf(h0n - bf2f(hh0)), ll1 = f2bf(h1n - bf2f(hh1));
      const unsigned hpack = (unsigned)hh0 | ((unsigned)hh1 << 16);
      const unsigned lpack = (unsigned)ll0 | ((unsigned)ll1 << 16);
      unsigned* hd = (unsigned*)&g_hfhi[t & 1][bg][pub];
      unsigned* ld = (unsigned*)&g_hflo[t & 1][bg][pub];
      asm volatile(
          "global_store_dword %0, %2, off sc0 sc1\n\t"
          "global_store_dword %1, %3, off sc0 sc1"
          :: "v"(hd), "v"(ld), "v"(hpack), "v"(lpack)
          : "memory");
      asm volatile("s_waitcnt vmcnt(0)" ::: "memory");  // drain own stores
      __syncthreads();
      if (tid == 0) {
        __hip_atomic_store(&g_flags2[bg][jt], base + (unsigned)t + 1u,
                           __ATOMIC_RELAXED, __HIP_MEMORY_SCOPE_AGENT);
      }
    }

    float2 hv; hv.x = h0n; hv.y = h1n;
    *(float2*)(out + ((size_t)t * BATCH + b0 + eb) * HSZ + j0 + ej) = hv;

    if (t == S_LEN - 1) {
      // h_T, c_T
      *(float2*)(out + (size_t)S_LEN * BATCH * HSZ + (size_t)(b0 + eb) * HSZ + j0 + ej) = hv;
      float2 cv; cv.x = creg0; cv.y = creg1;
      *(float2*)(out + (size_t)S_LEN * BATCH * HSZ + BATCH * HSZ
                 + (size_t)(b0 + eb) * HSZ + j0 + ej) = cv;
    }
  }
}

extern "C" void kernel_launch(void* const* d_in, const int* in_sizes, int n_in,
                              void* d_out, int out_size, void* d_ws, size_t ws_size,
                              hipStream_t stream) {
  (void)in_sizes; (void)n_in; (void)out_size; (void)ws_size;
  const float* input = (const float*)d_in[0];  // (512, 64, 512)
  const float* h0p   = (const float*)d_in[1];  // (64, 512)
  const float* c0p   = (const float*)d_in[2];  // (64, 512)
  const float* wih   = (const float*)d_in[3];  // (1, 2048, 512)
  const float* whhp  = (const float*)d_in[4];  // (1, 2048, 512)
  const float* bih   = (const float*)d_in[5];  // (1, 2048)
  const float* bhh   = (const float*)d_in[6];  // (1, 2048)
  float* outp  = (float*)d_out;
  float* xproj = (float*)d_ws;                 // 256 MB

  xcvt<<<dim3(8192), dim3(256), 0, stream>>>(input);
  wcvt<<<dim3(2048), dim3(256), 0, stream>>>(whhp, wih);
  xproj_mfma<<<dim3(4096), dim3(256), 0, stream>>>(bih, bhh, xproj);

  const float* xp = xproj;
  void* args[] = { (void*)&xp, (void*)&h0p, (void*)&c0p, (void*)&outp };
  hipLaunchCooperativeKernel((const void*)lstm_rec, dim3(64), dim3(256),
                             args, 0, stream);
}